// Round 11
// baseline (2043.646 us; speedup 1.0000x reference)
//
#include <hip/hip_runtime.h>

// Problem constants (match the reference).
#define BB 256
#define TT 2048
#define FF 64
#define UU 64
#define C3 192   // 3*U
#define CHX 16   // chunk granularity for the launcher

__device__ __forceinline__ float fast_sigmoid(float x) {
    return __builtin_amdgcn_rcpf(1.0f + __expf(-x));
}
__device__ __forceinline__ float fast_tanh(float x) {
    return 1.0f - 2.0f * __builtin_amdgcn_rcpf(__expf(2.0f * x) + 1.0f);
}
__device__ __forceinline__ float shflx(float v, int m) { return __shfl_xor(v, m, 64); }

#define QREP16(M) M(0) M(1) M(2) M(3) M(4) M(5) M(6) M(7) \
                  M(8) M(9) M(10) M(11) M(12) M(13) M(14) M(15)
#define REP16(M) QREP16(M)

// ---------------------------------------------------------------------------
// Kernel 1: x_proj = inputs @ kernel (+ bias folds), de-readlaned.
// 1024 blocks x 4 waves. 32-row tiles staged in double-buffered LDS; the
// input row reaches all 64 lanes via uniform-address ds_read_b128 broadcasts
// (no v_readlane -> no VALU->SGPR hazard chains, which made the old xproj
// run 2.7x over its issue estimate). Loads for tile t+1 issue before the
// compute of tile t, so the one barrier/tile never drains a fresh load.
// ---------------------------------------------------------------------------
__global__ __launch_bounds__(256)
void xproj2(const float* __restrict__ in, const float* __restrict__ kmat,
            const float* __restrict__ bias, float* __restrict__ xp,
            int t0, int tc) {
    __shared__ __align__(16) float at[2][32][FF];   // 16 KB
    const int tid  = threadIdx.x;
    const int lane = tid & 63;
    const int wv   = tid >> 6;
    const int lr   = tid >> 4;          // staging row 0..15
    const int col  = (tid & 15) * 4;    // staging col quad

    // 192 weights: kernel rows quad Q, column = lane, gates z/r/h.
#define DK(Q) float kzx##Q,kzy##Q,kzz##Q,kzw##Q, krx##Q,kry##Q,krz##Q,krw##Q, \
                    khx##Q,khy##Q,khz##Q,khw##Q;
    QREP16(DK)
#define IK(Q) { const int i_ = 4*(Q); \
    kzx##Q=kmat[(i_+0)*C3+lane];     kzy##Q=kmat[(i_+1)*C3+lane]; \
    kzz##Q=kmat[(i_+2)*C3+lane];     kzw##Q=kmat[(i_+3)*C3+lane]; \
    krx##Q=kmat[(i_+0)*C3+64+lane];  kry##Q=kmat[(i_+1)*C3+64+lane]; \
    krz##Q=kmat[(i_+2)*C3+64+lane];  krw##Q=kmat[(i_+3)*C3+64+lane]; \
    khx##Q=kmat[(i_+0)*C3+128+lane]; khy##Q=kmat[(i_+1)*C3+128+lane]; \
    khz##Q=kmat[(i_+2)*C3+128+lane]; khw##Q=kmat[(i_+3)*C3+128+lane]; }
    QREP16(IK)

    const float bz  = bias[lane]       + bias[C3 + lane];
    const float br  = bias[64 + lane]  + bias[C3 + 64 + lane];
    const float bh0 = bias[128 + lane];

    const int rows   = BB * tc;          // multiple of 4096
    const int stride = gridDim.x * 32;
    int tile = blockIdx.x * 32;
    if (tile >= rows) return;

    // prologue: stage tile into buf 0.
    {
        const int r1 = tile + lr;       const int b1 = r1 / tc, q1 = r1 - b1 * tc;
        const int r2 = tile + 16 + lr;  const int b2 = r2 / tc, q2 = r2 - b2 * tc;
        const float4 v1 = *(const float4*)&in[((size_t)b1 * TT + t0 + q1) * FF + col];
        const float4 v2 = *(const float4*)&in[((size_t)b2 * TT + t0 + q2) * FF + col];
        *(float4*)&at[0][lr][col]      = v1;
        *(float4*)&at[0][16 + lr][col] = v2;
    }
    __syncthreads();

    int cur = 0;
#pragma unroll 1
    for (; tile < rows; tile += stride) {
        const int  nxt = tile + stride;
        const bool hn  = nxt < rows;
        float4 n1, n2;
        if (hn) {   // issue next tile's loads now; consumed after ~3.4k cyc
            const int r1 = nxt + lr;       const int b1 = r1 / tc, q1 = r1 - b1 * tc;
            const int r2 = nxt + 16 + lr;  const int b2 = r2 / tc, q2 = r2 - b2 * tc;
            n1 = *(const float4*)&in[((size_t)b1 * TT + t0 + q1) * FF + col];
            n2 = *(const float4*)&in[((size_t)b2 * TT + t0 + q2) * FF + col];
        }

        // compute: wave wv owns rows wv*8 .. wv*8+7 of the tile.
#pragma unroll 1
        for (int k = 0; k < 8; ++k) {
            const float* ap = &at[cur][wv * 8 + k][0];
            float az = bz, ar = br, ah = bh0;
#define FK(Q) { const float4 hv = *(const float4*)(ap + 4*(Q)); \
    az = fmaf(hv.x, kzx##Q, az); az = fmaf(hv.y, kzy##Q, az); \
    az = fmaf(hv.z, kzz##Q, az); az = fmaf(hv.w, kzw##Q, az); \
    ar = fmaf(hv.x, krx##Q, ar); ar = fmaf(hv.y, kry##Q, ar); \
    ar = fmaf(hv.z, krz##Q, ar); ar = fmaf(hv.w, krw##Q, ar); \
    ah = fmaf(hv.x, khx##Q, ah); ah = fmaf(hv.y, khy##Q, ah); \
    ah = fmaf(hv.z, khz##Q, ah); ah = fmaf(hv.w, khw##Q, ah); }
            QREP16(FK)
            float* o = xp + (size_t)(tile + wv * 8 + k) * C3;
            o[lane] = az; o[64 + lane] = ar; o[128 + lane] = ah;
        }

        if (hn) {   // retire staging into the other buffer
            *(float4*)&at[cur ^ 1][lr][col]      = n1;
            *(float4*)&at[cur ^ 1][16 + lr][col] = n2;
        }
        __syncthreads();
        cur ^= 1;
    }
}

// ---------------------------------------------------------------------------
// Kernel 2: SINGLE-WAVE scan, de-readlaned. One wave per batch; lane j owns
// unit j; 192 U-weights resident (mask folded; mask in {0,2} -> bit-exact).
// h exchange: 1 ds_write_b32 + s_waitcnt lgkmcnt(0) (inline asm -- waits DS
// only, NO vmcnt drain, so the 4-deep x global-prefetch pipeline survives;
// rule-18 sched_barrier pins it) + 16 uniform-address ds_read_b128
// broadcasts. No barriers, no shuffles, no readlanes anywhere in the chain.
// hb double-buffered so step t+1's write can't pass step t's reads.
// ---------------------------------------------------------------------------
__global__ void __launch_bounds__(64, 1)
gru_scan2(const float* __restrict__ xp, const float* __restrict__ rk,
          const float* __restrict__ bias, const float* __restrict__ mask,
          const float* __restrict__ dw, const float* __restrict__ db,
          float* __restrict__ hws, float* __restrict__ out,
          int tc, int first, int last) {
    __shared__ __align__(16) float hb[2][64];
    const int b = blockIdx.x;
    const int j = threadIdx.x;

    const float* mzp = mask;
    const float* mrp = mask + (size_t)BB * UU;
    const float* mhp = mask + (size_t)2 * BB * UU;

    // 192 resident weights: U row-quad Q, column j, mask folded per row.
#define DU(Q) float uzx##Q,uzy##Q,uzz##Q,uzw##Q, urx##Q,ury##Q,urz##Q,urw##Q, \
                    uhx##Q,uhy##Q,uhz##Q,uhw##Q;
    QREP16(DU)
#define IU(Q) { const int i_ = 4*(Q); const size_t mb_ = (size_t)b * UU; \
    uzx##Q=rk[(i_+0)*C3+j]*mzp[mb_+i_+0];     uzy##Q=rk[(i_+1)*C3+j]*mzp[mb_+i_+1]; \
    uzz##Q=rk[(i_+2)*C3+j]*mzp[mb_+i_+2];     uzw##Q=rk[(i_+3)*C3+j]*mzp[mb_+i_+3]; \
    urx##Q=rk[(i_+0)*C3+64+j]*mrp[mb_+i_+0];  ury##Q=rk[(i_+1)*C3+64+j]*mrp[mb_+i_+1]; \
    urz##Q=rk[(i_+2)*C3+64+j]*mrp[mb_+i_+2];  urw##Q=rk[(i_+3)*C3+64+j]*mrp[mb_+i_+3]; \
    uhx##Q=rk[(i_+0)*C3+128+j]*mhp[mb_+i_+0]; uhy##Q=rk[(i_+1)*C3+128+j]*mhp[mb_+i_+1]; \
    uhz##Q=rk[(i_+2)*C3+128+j]*mhp[mb_+i_+2]; uhw##Q=rk[(i_+3)*C3+128+j]*mhp[mb_+i_+3]; }
    QREP16(IU)

    const float bh1 = bias[C3 + 128 + j];   // recurrent h-bias (inside r)

    const float* __restrict__ xpb = xp + (size_t)b * tc * C3;
    float h = first ? 0.0f : hws[(size_t)b * UU + j];

    // Prime the 4-deep x pipeline (rows 0..3).
    float xz0 = xpb[0*C3+j], xr0 = xpb[0*C3+64+j], xh0 = xpb[0*C3+128+j];
    float xz1 = xpb[1*C3+j], xr1 = xpb[1*C3+64+j], xh1 = xpb[1*C3+128+j];
    float xz2 = xpb[2*C3+j], xr2 = xpb[2*C3+64+j], xh2 = xpb[2*C3+128+j];
    float xz3 = xpb[3*C3+j], xr3 = xpb[3*C3+64+j], xh3 = xpb[3*C3+128+j];

#define FU(Q) { const float4 hv = *(const float4*)(hbp + 4*(Q)); \
    hz  = fmaf(hv.x, uzx##Q, hz);  hz  = fmaf(hv.y, uzy##Q, hz); \
    hz  = fmaf(hv.z, uzz##Q, hz);  hz  = fmaf(hv.w, uzw##Q, hz); \
    hr  = fmaf(hv.x, urx##Q, hr);  hr  = fmaf(hv.y, ury##Q, hr); \
    hr  = fmaf(hv.z, urz##Q, hr);  hr  = fmaf(hv.w, urw##Q, hr); \
    hah = fmaf(hv.x, uhx##Q, hah); hah = fmaf(hv.y, uhy##Q, hah); \
    hah = fmaf(hv.z, uhz##Q, hah); hah = fmaf(hv.w, uhw##Q, hah); }

#define SUB(S) { \
    hb[t_ & 1][j] = h; \
    asm volatile("s_waitcnt lgkmcnt(0)" ::: "memory"); \
    __builtin_amdgcn_sched_barrier(0); \
    float nxz_, nxr_, nxh_; \
    { const int rn_ = (t_ + 4 < tc) ? (t_ + 4) : (tc - 1); \
      const float* p_ = xpb + (size_t)rn_ * C3; \
      nxz_ = p_[j]; nxr_ = p_[64 + j]; nxh_ = p_[128 + j]; } \
    const float* hbp = &hb[t_ & 1][0]; \
    float hz = 0.f, hr = 0.f, hah = 0.f; \
    QREP16(FU) \
    const float z  = fast_sigmoid(hz + xz##S); \
    const float r  = fast_sigmoid(hr + xr##S); \
    const float hh = fast_tanh(fmaf(r, hah + bh1, xh##S)); \
    h = fmaf(z, h - hh, hh); \
    xz##S = nxz_; xr##S = nxr_; xh##S = nxh_; }

#pragma unroll 1
    for (int tb = 0; tb < tc; tb += 4) {
        { const int t_ = tb + 0; SUB(0) }
        { const int t_ = tb + 1; SUB(1) }
        { const int t_ = tb + 2; SUB(2) }
        { const int t_ = tb + 3; SUB(3) }
    }

    if (last) {
        float p = h * dw[j];
#pragma unroll
        for (int o = 32; o > 0; o >>= 1) p += __shfl_down(p, o, 64);
        if (j == 0) out[b] = p + db[0];
    } else {
        hws[(size_t)b * UU + j] = h;
    }
}

// ---------------------------------------------------------------------------
// Fallback (ws too small): v7 fused kernel, verbatim (1062 us, correct).
// ---------------------------------------------------------------------------
__global__ void __launch_bounds__(256, 1)
gru_fused7(const float* __restrict__ in, const float* __restrict__ kmat,
           const float* __restrict__ rk, const float* __restrict__ bias,
           const float* __restrict__ mask, const float* __restrict__ dw,
           const float* __restrict__ db, float* __restrict__ out) {
    __shared__ __align__(16) float hb[2][64];
    __shared__ __align__(16) float ab[2][32][FF];

    const int b    = blockIdx.x;
    const int lane = threadIdx.x & 63;
    const int wv   = threadIdx.x >> 6;
    const int sub  = lane >> 4;
    const int u    = lane & 15;
    const int j    = (wv << 4) + u;
    const int i0   = sub << 4;

    const float* mzp = mask;
    const float* mrp = mask + (size_t)BB * UU;
    const float* mhp = mask + (size_t)2 * BB * UU;
#define DECLW7(K) float fuz##K, fur##K, fuh##K, fkz##K, fkr##K, fkh##K;
    REP16(DECLW7)
#define INITW7(K) { const int i_ = i0 + (K); \
    fuz##K = rk[i_ * C3 + j]       * mzp[(size_t)b * UU + i_]; \
    fur##K = rk[i_ * C3 + 64 + j]  * mrp[(size_t)b * UU + i_]; \
    fuh##K = rk[i_ * C3 + 128 + j] * mhp[(size_t)b * UU + i_]; \
    fkz##K = kmat[i_ * C3 + j]; \
    fkr##K = kmat[i_ * C3 + 64 + j]; \
    fkh##K = kmat[i_ * C3 + 128 + j]; }
    REP16(INITW7)

    const float bzj  = bias[j]       + bias[C3 + j];
    const float brj  = bias[64 + j]  + bias[C3 + 64 + j];
    const float bh0j = bias[128 + j];
    const float bh1j = bias[C3 + 128 + j];

    const float* __restrict__ inb = in + (size_t)b * TT * FF;
    {
        const float* src = inb + (size_t)(wv * 8) * FF + lane;
        const float t0 = src[0 * FF], t1 = src[1 * FF], t2 = src[2 * FF],
                    t3 = src[3 * FF], t4 = src[4 * FF], t5 = src[5 * FF],
                    t6 = src[6 * FF], t7 = src[7 * FF];
        float* dst = &ab[0][wv * 8][lane];
        dst[0 * FF] = t0; dst[1 * FF] = t1; dst[2 * FF] = t2; dst[3 * FF] = t3;
        dst[4 * FF] = t4; dst[5 * FF] = t5; dst[6 * FF] = t6; dst[7 * FF] = t7;
    }
    if (wv == 0) hb[0][lane] = 0.0f;
    __syncthreads();

    float4 aA = *(const float4*)&ab[0][0][i0];
    float4 aB = *(const float4*)&ab[0][0][i0 + 4];
    float4 aC = *(const float4*)&ab[0][0][i0 + 8];
    float4 aD = *(const float4*)&ab[0][0][i0 + 12];
    float hown = 0.0f;

#pragma unroll 1
    for (int e = 0; e < TT; ++e) {
        const int  c  = e >> 5;
        const bool st = ((e & 31) == 0) && (c + 1 < TT / 32);
        float g0, g1, g2, g3, g4, g5, g6, g7;
        if (st) {
            const float* src = inb + ((size_t)(c + 1) * 32 + wv * 8) * FF + lane;
            g0 = src[0 * FF]; g1 = src[1 * FF]; g2 = src[2 * FF]; g3 = src[3 * FF];
            g4 = src[4 * FF]; g5 = src[5 * FF]; g6 = src[6 * FF]; g7 = src[7 * FF];
        }
        const float4 hA = *(const float4*)&hb[e & 1][i0];
        const float4 hB = *(const float4*)&hb[e & 1][i0 + 4];
        const float4 hC = *(const float4*)&hb[e & 1][i0 + 8];
        const float4 hD = *(const float4*)&hb[e & 1][i0 + 12];

        float az = 0.f, ar = 0.f, axh = 0.f;
#define FMA_A7(K, AV) { az = fmaf(AV, fkz##K, az); ar = fmaf(AV, fkr##K, ar); \
                        axh = fmaf(AV, fkh##K, axh); }
        FMA_A7(0,  aA.x) FMA_A7(1,  aA.y) FMA_A7(2,  aA.z) FMA_A7(3,  aA.w)
        FMA_A7(4,  aB.x) FMA_A7(5,  aB.y) FMA_A7(6,  aB.z) FMA_A7(7,  aB.w)
        FMA_A7(8,  aC.x) FMA_A7(9,  aC.y) FMA_A7(10, aC.z) FMA_A7(11, aC.w)
        FMA_A7(12, aD.x) FMA_A7(13, aD.y) FMA_A7(14, aD.z) FMA_A7(15, aD.w)

        float hz = 0.f, hr = 0.f, hah = 0.f;
#define FMA_H7(K, HV) { hz = fmaf(HV, fuz##K, hz); hr = fmaf(HV, fur##K, hr); \
                        hah = fmaf(HV, fuh##K, hah); }
        FMA_H7(0,  hA.x) FMA_H7(1,  hA.y) FMA_H7(2,  hA.z) FMA_H7(3,  hA.w)
        FMA_H7(4,  hB.x) FMA_H7(5,  hB.y) FMA_H7(6,  hB.z) FMA_H7(7,  hB.w)
        FMA_H7(8,  hC.x) FMA_H7(9,  hC.y) FMA_H7(10, hC.z) FMA_H7(11, hC.w)
        FMA_H7(12, hD.x) FMA_H7(13, hD.y) FMA_H7(14, hD.z) FMA_H7(15, hD.w)

        float sz = az + hz, sr = ar + hr, sxh = axh, sah = hah;
        { const float t0 = shflx(sz, 16), t1 = shflx(sr, 16),
                      t2 = shflx(sxh, 16), t3 = shflx(sah, 16);
          sz += t0; sr += t1; sxh += t2; sah += t3; }
        { const float t0 = shflx(sz, 32), t1 = shflx(sr, 32),
                      t2 = shflx(sxh, 32), t3 = shflx(sah, 32);
          sz += t0; sr += t1; sxh += t2; sah += t3; }

        const float z  = fast_sigmoid(sz + bzj);
        const float r  = fast_sigmoid(sr + brj);
        const float hh = fast_tanh(fmaf(r, sah + bh1j, sxh + bh0j));
        hown = fmaf(z, hown - hh, hh);
        if (sub == 0) hb[(e + 1) & 1][j] = hown;

        const int rn = (e + 1 < TT) ? (e + 1) : (TT - 1);
        const float* ap = &ab[(rn >> 5) & 1][rn & 31][i0];
        aA = *(const float4*)(ap);
        aB = *(const float4*)(ap + 4);
        aC = *(const float4*)(ap + 8);
        aD = *(const float4*)(ap + 12);

        if (st) {
            float* dst = &ab[(c + 1) & 1][wv * 8][lane];
            dst[0 * FF] = g0; dst[1 * FF] = g1; dst[2 * FF] = g2; dst[3 * FF] = g3;
            dst[4 * FF] = g4; dst[5 * FF] = g5; dst[6 * FF] = g6; dst[7 * FF] = g7;
        }
        __syncthreads();
    }

    if (wv == 0) {
        float p = hb[0][lane] * dw[lane];
#pragma unroll
        for (int o = 32; o > 0; o >>= 1) p += __shfl_down(p, o, 64);
        if (lane == 0) out[b] = p + db[0];
    }
}

// ---------------------------------------------------------------------------
extern "C" void kernel_launch(void* const* d_in, const int* in_sizes, int n_in,
                              void* d_out, int out_size, void* d_ws, size_t ws_size,
                              hipStream_t stream) {
    (void)in_sizes; (void)n_in; (void)out_size;
    const float* inputs = (const float*)d_in[0];
    const float* kmat   = (const float*)d_in[1];
    const float* rk     = (const float*)d_in[2];
    const float* bias   = (const float*)d_in[3];
    const float* dw     = (const float*)d_in[4];
    const float* db     = (const float*)d_in[5];
    const float* mask   = (const float*)d_in[6];
    float* out = (float*)d_out;

    const size_t h_bytes   = (size_t)BB * UU * sizeof(float);   // 64 KB
    const size_t row_bytes = (size_t)BB * C3 * sizeof(float);   // 192 KB / step

    // capacity in timesteps for the xp buffer (multiple of CHX)
    int cap = 0;
    if (ws_size > h_bytes)
        cap = (int)((ws_size - h_bytes) / row_bytes) & ~(CHX - 1);
    if (cap > TT) cap = TT;

    if (cap >= 256) {
        float* hws = (float*)d_ws;
        float* xp  = (float*)((char*)d_ws + h_bytes);
        const int nch  = (TT + cap - 1) / cap;
        int base = (TT + nch - 1) / nch;
        base = (base + CHX - 1) & ~(CHX - 1);        // multiple of 16, <= cap
        int t0 = 0;
        while (t0 < TT) {
            const int cur = (TT - t0) < base ? (TT - t0) : base;   // mult of 16
            xproj2<<<1024, 256, 0, stream>>>(inputs, kmat, bias, xp, t0, cur);
            gru_scan2<<<BB, 64, 0, stream>>>(xp, rk, bias, mask, dw, db, hws, out,
                                             cur, t0 == 0 ? 1 : 0,
                                             (t0 + cur == TT) ? 1 : 0);
            t0 += cur;
        }
    } else {
        gru_fused7<<<BB, 256, 0, stream>>>(inputs, kmat, rk, bias, mask, dw, db, out);
    }
}